// Round 3
// baseline (474.228 us; speedup 1.0000x reference)
//
#include <hip/hip_runtime.h>

#define NCH 32

typedef __attribute__((ext_vector_type(8))) __bf16 bf16x8;
typedef __attribute__((ext_vector_type(4))) float  f32x4;

// Split 8 fp32 values into bf16 hi + bf16 lo (residual) fragments.
// ah*bh + al*bh + ah*bl reconstructs the fp32 product to ~2^-16 relative.
static __device__ __forceinline__ void split8(const float* x, bf16x8& hi, bf16x8& lo)
{
#pragma unroll
    for (int e = 0; e < 8; ++e) {
        __bf16 h = (__bf16)x[e];
        hi[e] = h;
        lo[e] = (__bf16)(x[e] - (float)h);
    }
}

static __device__ __forceinline__ void mfma3(
    const bf16x8& ah, const bf16x8& al,
    const bf16x8& wh, const bf16x8& wl, f32x4& acc)
{
    acc = __builtin_amdgcn_mfma_f32_16x16x32_bf16(ah, wh, acc, 0, 0, 0);
    acc = __builtin_amdgcn_mfma_f32_16x16x32_bf16(al, wh, acc, 0, 0, 0);
    acc = __builtin_amdgcn_mfma_f32_16x16x32_bf16(ah, wl, acc, 0, 0, 0);
}

// Factorized 1D sparse conv as MFMA GEMM over 16-point tiles.
// A fragment (16x32, K=channels): lane holds f[row = tb + (lane&15)][c0..c0+7],
//   c0 = (lane>>4)*8.  Invalid rows zeroed (missing neighbor / tail).
// B fragment (32x16): lane holds W[k][c0..c0+7][d = (lane&15) + 16*half].
// C/D: lane holds out[tb + (lane>>4)*4 + r][(lane&15) + 16*half], r=0..3.
// Tap 1 is the identity map (offset 0) -> own row, no index load.
// Software pipeline: each iteration issues current tile's 6 row-loads at the
// top (addresses from indices prefetched LAST iteration, clamped so issue is
// unconditional), then prefetches next tile's indices, then computes.
// do_stats: fused per-channel sum/sumsq, block LDS combine, 64 atomics/block.
__global__ __launch_bounds__(256) void conv_mfma_kernel(
    const float* __restrict__ f, const float* __restrict__ W,
    const int* __restrict__ idx, float* __restrict__ out, int n,
    float* __restrict__ stats, int do_stats)
{
    __shared__ float red[4][4][16];

    const int lane = threadIdx.x & 63;
    const int wv   = threadIdx.x >> 6;
    const int r16  = lane & 15;
    const int g    = lane >> 4;
    const int c0   = g * 8;

    // B fragments: 3 taps x 2 output halves, hi/lo split (held in VGPRs).
    bf16x8 bh[3][2], bl[3][2];
#pragma unroll
    for (int k = 0; k < 3; ++k) {
#pragma unroll
        for (int h = 0; h < 2; ++h) {
            float w8[8];
#pragma unroll
            for (int e = 0; e < 8; ++e)
                w8[e] = W[k * NCH * NCH + (c0 + e) * NCH + (h * 16 + r16)];
            split8(w8, bh[k][h], bl[k][h]);
        }
    }

    const int ntiles = (n + 15) >> 4;
    const int stride = gridDim.x * 4;
    int tile = blockIdx.x * 4 + wv;

    float s0 = 0.f, q0 = 0.f, s1 = 0.f, q1 = 0.f;

    // prologue: load indices for the first tile
    int  ci0 = 0, ci2 = 0;
    bool cm0 = false, cm2 = false;
    if (tile < ntiles) {
        int p  = (tile << 4) + r16;
        int pc = p < n ? p : (n - 1);
        ci0 = idx[pc];
        ci2 = idx[2 * (size_t)n + pc];
        cm0 = (p < n) && (ci0 < n);
        cm2 = (p < n) && (ci2 < n);
    }

    for (; tile < ntiles; tile += stride) {
        const int  tb  = tile << 4;
        const int  p   = tb + r16;
        const bool pin = (p < n);
        const int  pc  = pin ? p : (n - 1);

        // ---- issue all 6 row loads immediately (addresses ready) ----
        const float4* rown = (const float4*)(f + (size_t)pc * NCH + c0);
        float4 o0 = rown[0], o1 = rown[1];
        const float4* rg0 = (const float4*)(f + (size_t)(cm0 ? ci0 : 0) * NCH + c0);
        float4 ga0 = rg0[0], ga1 = rg0[1];
        const float4* rg2 = (const float4*)(f + (size_t)(cm2 ? ci2 : 0) * NCH + c0);
        float4 gb0 = rg2[0], gb1 = rg2[1];

        const bool am0 = __any(cm0);
        const bool am2 = __any(cm2);

        // ---- prefetch next tile's indices (hidden under compute) ----
        int  ni0 = 0, ni2 = 0;
        bool nm0 = false, nm2 = false;
        const int tn = tile + stride;
        if (tn < ntiles) {
            int pn  = (tn << 4) + r16;
            int pnc = pn < n ? pn : (n - 1);
            ni0 = idx[pnc];
            ni2 = idx[2 * (size_t)n + pnc];
            nm0 = (pn < n) && (ni0 < n);
            nm2 = (pn < n) && (ni2 < n);
        }

        f32x4 a0 = {0.f, 0.f, 0.f, 0.f};
        f32x4 a1 = {0.f, 0.f, 0.f, 0.f};

        // ---- tap 1: identity (own row) ----
        {
            float m = pin ? 1.f : 0.f;
            float x[8] = {o0.x * m, o0.y * m, o0.z * m, o0.w * m,
                          o1.x * m, o1.y * m, o1.z * m, o1.w * m};
            bf16x8 ah, al;
            split8(x, ah, al);
            mfma3(ah, al, bh[1][0], bl[1][0], a0);
            mfma3(ah, al, bh[1][1], bl[1][1], a1);
        }
        // ---- tap 0 ----
        if (am0) {
            float m = cm0 ? 1.f : 0.f;
            float x[8] = {ga0.x * m, ga0.y * m, ga0.z * m, ga0.w * m,
                          ga1.x * m, ga1.y * m, ga1.z * m, ga1.w * m};
            bf16x8 ah, al;
            split8(x, ah, al);
            mfma3(ah, al, bh[0][0], bl[0][0], a0);
            mfma3(ah, al, bh[0][1], bl[0][1], a1);
        }
        // ---- tap 2 ----
        if (am2) {
            float m = cm2 ? 1.f : 0.f;
            float x[8] = {gb0.x * m, gb0.y * m, gb0.z * m, gb0.w * m,
                          gb1.x * m, gb1.y * m, gb1.z * m, gb1.w * m};
            bf16x8 ah, al;
            split8(x, ah, al);
            mfma3(ah, al, bh[2][0], bl[2][0], a0);
            mfma3(ah, al, bh[2][1], bl[2][1], a1);
        }

        // ---- store C: row = tb + g*4 + r, col = r16 / r16+16 ----
#pragma unroll
        for (int r = 0; r < 4; ++r) {
            int prow = tb + g * 4 + r;
            if (prow < n) {
                float* o = out + (size_t)prow * NCH + r16;
                o[0]  = a0[r];
                o[16] = a1[r];
            }
        }

        if (do_stats) {
#pragma unroll
            for (int r = 0; r < 4; ++r) {
                s0 += a0[r]; q0 = fmaf(a0[r], a0[r], q0);
                s1 += a1[r]; q1 = fmaf(a1[r], a1[r], q1);
            }
        }

        ci0 = ni0; ci2 = ni2; cm0 = nm0; cm2 = nm2;
    }

    if (do_stats) {
        // lanes with the same (lane&15) hold the same channel: xor-16/32 reduce
        s0 += __shfl_xor(s0, 16); s0 += __shfl_xor(s0, 32);
        q0 += __shfl_xor(q0, 16); q0 += __shfl_xor(q0, 32);
        s1 += __shfl_xor(s1, 16); s1 += __shfl_xor(s1, 32);
        q1 += __shfl_xor(q1, 16); q1 += __shfl_xor(q1, 32);
        if (lane < 16) {
            red[wv][0][r16] = s0;
            red[wv][1][r16] = q0;
            red[wv][2][r16] = s1;
            red[wv][3][r16] = q1;
        }
        __syncthreads();
        if (threadIdx.x < 64) {
            int vsel = threadIdx.x >> 4;   // 0:s lo, 1:q lo, 2:s hi, 3:q hi
            int ch   = threadIdx.x & 15;
            float t = red[0][vsel][ch] + red[1][vsel][ch] +
                      red[2][vsel][ch] + red[3][vsel][ch];
            int channel = (vsel & 2) ? (ch + 16) : ch;
            atomicAdd(stats + ((vsel & 1) ? NCH : 0) + channel, t);
        }
    }
}

// BatchNorm (batch stats) + ReLU, in place on h [n,32]. One float4 per thread.
__global__ __launch_bounds__(256) void bn_relu_kernel(
    float* h, const float* __restrict__ stats,
    const float* __restrict__ gamma, const float* __restrict__ beta, int n)
{
    long tid = (long)blockIdx.x * 256 + threadIdx.x;
    long total4 = (long)n * NCH / 4;
    if (tid >= total4) return;

    int ch0 = ((int)(tid & 7)) * 4;
    float inv_n = 1.f / (float)n;

    float4 v = ((const float4*)h)[tid];
    float r[4] = {v.x, v.y, v.z, v.w};
#pragma unroll
    for (int j = 0; j < 4; ++j) {
        int ch = ch0 + j;
        float mean = stats[ch] * inv_n;
        float var = stats[NCH + ch] * inv_n - mean * mean;
        float scale = gamma[ch] * rsqrtf(var + 1e-5f);
        float shift = beta[ch] - mean * scale;
        float o = fmaf(r[j], scale, shift);
        r[j] = o > 0.f ? o : 0.f;
    }
    float4 o4;
    o4.x = r[0]; o4.y = r[1]; o4.z = r[2]; o4.w = r[3];
    ((float4*)h)[tid] = o4;
}

extern "C" void kernel_launch(void* const* d_in, const int* in_sizes, int n_in,
                              void* d_out, int out_size, void* d_ws, size_t ws_size,
                              hipStream_t stream)
{
    const float* feats = (const float*)d_in[0];
    const float* W1    = (const float*)d_in[1];
    const float* W2    = (const float*)d_in[2];
    const float* W3    = (const float*)d_in[3];
    const float* gamma = (const float*)d_in[4];
    const float* beta  = (const float*)d_in[5];
    const int*   nbr   = (const int*)d_in[6];   // [3 axes][3 taps][n]

    int n = in_sizes[0] / NCH;

    float* hout  = (float*)d_out;                // h1, then h3, then final out
    float* h2    = (float*)d_ws;                 // n*32 floats
    float* stats = h2 + (size_t)n * NCH;         // 64 floats

    // 4096 blocks x 4 waves = 16384 waves over 8192 slots -> occupancy not
    // grid-capped (round-2 launched 1024 -> 50% cap); ~3.8 tiles/wave.
    int ntiles = (n + 15) >> 4;
    int cblocks = (ntiles + 3) / 4;
    if (cblocks > 4096) cblocks = 4096;

    // conv1: axis 2 (z), feats -> d_out
    conv_mfma_kernel<<<cblocks, 256, 0, stream>>>(feats, W1, nbr + (size_t)2 * 3 * n,
                                                  hout, n, nullptr, 0);
    // conv2: axis 1 (y), d_out -> ws
    conv_mfma_kernel<<<cblocks, 256, 0, stream>>>(hout, W2, nbr + (size_t)1 * 3 * n,
                                                  h2, n, nullptr, 0);

    // zero BN accumulators before conv3 (which fuses the stats reduction)
    hipMemsetAsync(stats, 0, 2 * NCH * sizeof(float), stream);

    // conv3: axis 0 (x), ws -> d_out, with fused per-channel sum/sumsq
    conv_mfma_kernel<<<cblocks, 256, 0, stream>>>(h2, W3, nbr + (size_t)0 * 3 * n,
                                                  hout, n, stats, 1);

    // BN + ReLU in place
    long total4 = (long)n * NCH / 4;
    int nblocks = (int)((total4 + 255) / 256);
    bn_relu_kernel<<<nblocks, 256, 0, stream>>>(hout, stats, gamma, beta, n);
}